// Round 1
// baseline (348.665 us; speedup 1.0000x reference)
//
#include <hip/hip_runtime.h>
#include <hip/hip_bf16.h>

typedef unsigned short u16;
typedef unsigned int u32;
typedef __attribute__((ext_vector_type(8))) short short8;
typedef __attribute__((ext_vector_type(4))) float float4v;

#define T_DIM 2048
#define D_DIM 2048
#define N_DIM 11264
#define BD    5632
#define KE    256   // extra K from LoRA fold-in (L*R = 16*16)

__device__ __forceinline__ u16 f2bf(float f) {
    union { float f; u32 u; } v; v.f = f;
    u32 u = v.u;
    return (u16)((u + 0x7fffu + ((u >> 16) & 1u)) >> 16);  // RNE, inputs finite
}

__device__ __forceinline__ void gld16(const u16* g, u16* l) {
    // async global->LDS, 16B per lane; LDS dest = wave-uniform base + lane*16
    __builtin_amdgcn_global_load_lds((const __attribute__((address_space(1))) void*)g,
                                     (__attribute__((address_space(3))) void*)l, 16, 0, 0);
}

// ---------------------------------------------------------------------------
// Prep kernel (f32 inputs), block ranges (latency-heavy parts first):
//  bid [0,2048):      xa[t] = x[t,:].A[l_t] (f32, coalesced wave loads),
//                     scatter to dense xahat0/xahat1 (T x 256 bf16)
//  bid [2048,4864):   transpose B (256 x 11264 f32) -> BT (11264 x 256 bf16)
//  bid [4864,5376):   X f32 -> Xb bf16 (32 elems/thread)
//  bid [5376,8192):   W f32 -> Wb bf16 (32 elems/thread)
// ---------------------------------------------------------------------------
__global__ __launch_bounds__(256) void prep_kernel(
    const float* __restrict__ Xf, const float* __restrict__ Wf,
    const float* __restrict__ Af, const float* __restrict__ Bf,
    const int* __restrict__ widx,
    u16* __restrict__ Wb, u16* __restrict__ Xb,
    u16* __restrict__ XH0, u16* __restrict__ XH1, u16* __restrict__ BT)
{
    const int bid = blockIdx.x;
    const int tid = threadIdx.x;

    __shared__ float lx[D_DIM];          // staged x row (8 KB)
    __shared__ float red[4][8][4];
    __shared__ float xa[32];
    __shared__ u16 tile[32][33];

    if (bid < 2048) {
        // ---- xa for token t ----
        const int t = bid;
        const int l = widx[t];
        const float4* xr = (const float4*)(Xf + (size_t)t * D_DIM);
        ((float4*)lx)[tid]       = xr[tid];
        ((float4*)lx)[tid + 256] = xr[tid + 256];
        __syncthreads();

        const int wave = tid >> 6, lane = tid & 63;
        const int rowg = lane >> 3, chunk = lane & 7;
        // wave-load: 8 consecutive rows x 128 B, fully coalesced 1 KB
        const float* abase = Af + (size_t)l * (D_DIM * 32) + chunk * 4;
        float accx = 0.f, accy = 0.f, accz = 0.f, accw = 0.f;
#pragma unroll 4
        for (int i = 0; i < 64; ++i) {
            const int row = wave * 512 + i * 8 + rowg;
            const float4 av = *(const float4*)(abase + (size_t)row * 32);
            const float xf = lx[row];
            accx += xf * av.x; accy += xf * av.y;
            accz += xf * av.z; accw += xf * av.w;
        }
        // reduce across the 8 rowgroups (xor 8/16/32)
#pragma unroll
        for (int off = 8; off <= 32; off <<= 1) {
            accx += __shfl_xor(accx, off);
            accy += __shfl_xor(accy, off);
            accz += __shfl_xor(accz, off);
            accw += __shfl_xor(accw, off);
        }
        if (rowg == 0) {
            red[wave][chunk][0] = accx; red[wave][chunk][1] = accy;
            red[wave][chunk][2] = accz; red[wave][chunk][3] = accw;
        }
        __syncthreads();
        if (tid < 32) {
            const int c = tid >> 2, j = tid & 3;
            xa[c * 4 + j] = red[0][c][j] + red[1][c][j] + red[2][c][j] + red[3][c][j];
        }
        __syncthreads();
        // scatter: k = tid; xahat_h[t, l'*16+r] = (l'==l) ? xa[h*16+r] : 0
        const int k = tid, kl = k >> 4, r = k & 15;
        const bool hit = (kl == l);
        XH0[(size_t)t * KE + k] = hit ? f2bf(xa[r])      : (u16)0;
        XH1[(size_t)t * KE + k] = hit ? f2bf(xa[16 + r]) : (u16)0;
    } else if (bid < 4864) {
        // ---- 32x32 tiled transpose + convert: BT[n,k] = bf16(B[k,n]) ----
        const int b = bid - 2048;
        const int nb = b >> 3;   // 0..351
        const int kb = b & 7;    // 0..7
        const int tx = tid & 31, ty = tid >> 5;
        const int n = nb * 32 + tx;
#pragma unroll
        for (int i = 0; i < 4; ++i) {
            const int kk = kb * 32 + ty + i * 8;
            tile[ty + i * 8][tx] = f2bf(Bf[(size_t)kk * N_DIM + n]);
        }
        __syncthreads();
        const int k2 = kb * 32 + tx;
#pragma unroll
        for (int i = 0; i < 4; ++i) {
            const int n2 = nb * 32 + ty + i * 8;
            BT[(size_t)n2 * KE + k2] = tile[tx][ty + i * 8];
        }
    } else if (bid < 5376) {
        // ---- X convert: 32 f32/thread ----
        const size_t base = ((size_t)(bid - 4864) * 256 + tid) * 32;
        const float4* p = (const float4*)(Xf + base);
        float4 v[8];
#pragma unroll
        for (int i = 0; i < 8; ++i) v[i] = p[i];
#pragma unroll
        for (int i = 0; i < 4; ++i) {
            short8 o;
            o[0] = (short)f2bf(v[2*i].x);   o[1] = (short)f2bf(v[2*i].y);
            o[2] = (short)f2bf(v[2*i].z);   o[3] = (short)f2bf(v[2*i].w);
            o[4] = (short)f2bf(v[2*i+1].x); o[5] = (short)f2bf(v[2*i+1].y);
            o[6] = (short)f2bf(v[2*i+1].z); o[7] = (short)f2bf(v[2*i+1].w);
            *(short8*)(Xb + base + i * 8) = o;
        }
    } else {
        // ---- W convert: 32 f32/thread ----
        const size_t base = ((size_t)(bid - 5376) * 256 + tid) * 32;
        const float4* p = (const float4*)(Wf + base);
        float4 v[8];
#pragma unroll
        for (int i = 0; i < 8; ++i) v[i] = p[i];
#pragma unroll
        for (int i = 0; i < 4; ++i) {
            short8 o;
            o[0] = (short)f2bf(v[2*i].x);   o[1] = (short)f2bf(v[2*i].y);
            o[2] = (short)f2bf(v[2*i].z);   o[3] = (short)f2bf(v[2*i].w);
            o[4] = (short)f2bf(v[2*i+1].x); o[5] = (short)f2bf(v[2*i+1].y);
            o[6] = (short)f2bf(v[2*i+1].z); o[7] = (short)f2bf(v[2*i+1].w);
            *(short8*)(Wb + base + i * 8) = o;
        }
    }
}

// ---------------------------------------------------------------------------
// Main GEMM: out[m,n] = sum_k xb[m,k] wb[n,k]  (K=2048, bf16)
//                     + sum_k xahat_h[m,k] BT[n,k]  (K=256, h by n-half)
//
// 256x256 tile, BK=64, 512 threads = 8 waves (2M x 4N), per-wave 128x64 out.
// Pipelined: stage tile kt+1 (8x global_load_lds) -> s_waitcnt vmcnt(8)
// (never 0 in the main loop: next tile's loads stay in flight across the
// barriers) -> raw s_barrier -> 4 clusters of 16 MFMA with s_setprio(1)
// around each -> raw s_barrier.  LDS double-buffered 128 KB, 1 block/CU.
//
// LDS swizzle (stage + read must match, involution): physical 16B chunk p
// of row r holds global chunk p ^ (r&7); staged by pre-swizzling the global
// source address (LDS dest stays lane-linear as global_load_lds requires).
// Fragment ds_read_b128 then lands 8 lanes per bank-quad = balanced, no
// serialization (linear [256][64] would be 16-way conflicted).
// ---------------------------------------------------------------------------
__global__ __launch_bounds__(512, 2) void gemm_kernel(
    const u16* __restrict__ X, const u16* __restrict__ W,
    const u16* __restrict__ XH0, const u16* __restrict__ XH1,
    const u16* __restrict__ BT, float* __restrict__ OUT)
{
    __shared__ __align__(16) u16 lds[4][256 * 64];  // [0..1]=A buf, [2..3]=B buf

    const int tid  = threadIdx.x;
    const int lane = tid & 63;
    const int wave = tid >> 6;          // 0..7
    const int wm   = wave >> 2;         // 0..1  (M half)
    const int wn   = wave & 3;          // 0..3  (N quarter)
    const int q    = lane >> 4;         // 0..3
    const int c16  = lane & 15;

    // XCD-aware swizzle: 352 = 8 XCDs * 44; each XCD owns one bm row panel
    const int bid = blockIdx.x;
    const int swz = (bid & 7) * 44 + (bid >> 3);
    const int bm  = swz / 44;
    const int bn  = swz % 44;
    const int m0  = bm * 256, n0 = bn * 256;

    // ---- staging geometry (per gld16: 64 lanes x 16B = 8 rows x 128B) ----
    const int lrow = lane >> 3;                 // row within 8-row group
    const int gch  = (lane & 7) ^ lrow;         // pre-swizzled source chunk
    const int srow = wave * 8 + lrow;           // tile row (+ i*64 per instr)

    const u16* gA = X + (size_t)(m0 + srow) * D_DIM + gch * 8;
    const u16* gB = W + (size_t)(n0 + srow) * D_DIM + gch * 8;
    const u16* XH = (n0 < BD) ? XH0 : XH1;      // tiles never straddle halves
    const u16* eA = XH + (size_t)(m0 + srow) * KE + gch * 8;
    const u16* eB = BT + (size_t)(n0 + srow) * KE + gch * 8;

    const int ldst = wave * 8 * 64;             // wave-uniform LDS stage base

    float4v acc[8][4] = {};

    auto stage = [&](int kt) {
        u16* la = &lds[kt & 1][0] + ldst;
        u16* lb = &lds[2 + (kt & 1)][0] + ldst;
        if (kt < 32) {
            const u16* pa = gA + kt * 64;
            const u16* pb = gB + kt * 64;
#pragma unroll
            for (int i = 0; i < 4; ++i) {
                gld16(pa + (size_t)(i * 64) * D_DIM, la + i * 64 * 64);
                gld16(pb + (size_t)(i * 64) * D_DIM, lb + i * 64 * 64);
            }
        } else {
            const u16* pa = eA + (kt - 32) * 64;
            const u16* pb = eB + (kt - 32) * 64;
#pragma unroll
            for (int i = 0; i < 4; ++i) {
                gld16(pa + (size_t)(i * 64) * KE, la + i * 64 * 64);
                gld16(pb + (size_t)(i * 64) * KE, lb + i * 64 * 64);
            }
        }
    };

    auto compute = [&](int kt) {
        const u16* la = &lds[kt & 1][0];
        const u16* lb = &lds[2 + (kt & 1)][0];
#pragma unroll
        for (int ks = 0; ks < 2; ++ks) {
            const int ph = ((ks * 4 + q) ^ (c16 & 7)) * 8;  // swizzled chunk (u16)
            short8 bfr[4];
#pragma unroll
            for (int fn = 0; fn < 4; ++fn)
                bfr[fn] = *(const short8*)(lb + (wn * 64 + fn * 16 + c16) * 64 + ph);
#pragma unroll
            for (int h = 0; h < 2; ++h) {       // two 16-MFMA clusters per ks
                short8 afr[4];
#pragma unroll
                for (int j = 0; j < 4; ++j)
                    afr[j] = *(const short8*)(la + (wm * 128 + (h * 4 + j) * 16 + c16) * 64 + ph);
                __builtin_amdgcn_s_setprio(1);
#pragma unroll
                for (int j = 0; j < 4; ++j)
#pragma unroll
                    for (int fn = 0; fn < 4; ++fn)
                        acc[h * 4 + j][fn] = __builtin_amdgcn_mfma_f32_16x16x32_bf16(
                            afr[j], bfr[fn], acc[h * 4 + j][fn], 0, 0, 0);
                __builtin_amdgcn_s_setprio(0);
            }
        }
    };

    stage(0);
    for (int kt = 0; kt < 36; ++kt) {           // 32 main + 4 LoRA K-tiles
        if (kt < 35) {
            stage(kt + 1);                      // 8 loads for next tile in flight
            asm volatile("s_waitcnt vmcnt(8)" ::: "memory");   // wait tile kt only
        } else {
            asm volatile("s_waitcnt vmcnt(0)" ::: "memory");   // drain last tile
        }
        __builtin_amdgcn_sched_barrier(0);
        __builtin_amdgcn_s_barrier();
        __builtin_amdgcn_sched_barrier(0);
        compute(kt);
        __builtin_amdgcn_sched_barrier(0);      // keep MFMAs + their lgkm waits here
        __builtin_amdgcn_s_barrier();
        __builtin_amdgcn_sched_barrier(0);
    }

    // epilogue: C/D layout col = lane&15, row = (lane>>4)*4 + reg
#pragma unroll
    for (int fm = 0; fm < 8; ++fm) {
        const size_t row = (size_t)(m0 + wm * 128 + fm * 16 + q * 4);
#pragma unroll
        for (int fn = 0; fn < 4; ++fn) {
            const int col = n0 + wn * 64 + fn * 16 + c16;
#pragma unroll
            for (int r = 0; r < 4; ++r)
                OUT[(row + r) * N_DIM + col] = acc[fm][fn][r];
        }
    }
}

extern "C" void kernel_launch(void* const* d_in, const int* in_sizes, int n_in,
                              void* d_out, int out_size, void* d_ws, size_t ws_size,
                              hipStream_t stream) {
    const float* Xf  = (const float*)d_in[0];   // (2048, 2048) f32
    const float* Wf  = (const float*)d_in[1];   // (11264, 2048) f32
    const float* Af  = (const float*)d_in[2];   // (16, 2048, 32) f32
    const float* Bf  = (const float*)d_in[3];   // (16, 16, 11264) f32
    const int* widx  = (const int*)d_in[4];     // (2048,) int32 (JAX x64 off)
    float* OUT = (float*)d_out;                 // (2048, 11264) f32

    u16* Wb  = (u16*)d_ws;                            // 11264x2048 bf16 (46.1 MB)
    u16* Xb  = Wb + (size_t)N_DIM * D_DIM;            // 2048x2048 bf16 (8.4 MB)
    u16* XH0 = Xb + (size_t)T_DIM * D_DIM;            // 2048x256 bf16 (1 MB)
    u16* XH1 = XH0 + (size_t)T_DIM * KE;              // 2048x256 bf16 (1 MB)
    u16* BT  = XH1 + (size_t)T_DIM * KE;              // 11264x256 bf16 (5.5 MB)

    prep_kernel<<<dim3(8192), dim3(256), 0, stream>>>(Xf, Wf, Af, Bf, widx,
                                                      Wb, Xb, XH0, XH1, BT);
    gemm_kernel<<<dim3(44 * 8), dim3(512), 0, stream>>>(
        Xb, Wb, XH0, XH1, BT, OUT);
}